// Round 1
// baseline (360.074 us; speedup 1.0000x reference)
//
#include <hip/hip_runtime.h>
#include <hip/hip_bf16.h>

// ---------------------------------------------------------------------------
// FFT butterfly attention. delta = x_a^T P (x_a - x_b), P = scale*Wq*Wk^T
// (bf16, MFMA prep). w0 = sigmoid(delta); v' = mix(va, vb).
//
// NEW SCHEME (this round): transposed GEMM Gt = P^T @ Xa^T so the pair index
// lands in lane15 and the dim index in (quad,reg) of the MFMA C layout.
// Wave w (nt = w&3, mh = w>>2) computes Gt for pairs nt*16..+15 over k-half
// mh*64..+63 -> 16 MFMAs, acc stays in registers. delta dot is then IN-WAVE:
// per-lane 16 FMAs vs dx = xa-xb (ds_read_b64 from xb), xor16+xor32 reduce,
// one scalar LDS write per k-half. gbuf is GONE (-33.8 KB LDS), and the
// GEMM->dot barrier is gone: ONE barrier per stage (wt double-buffered).
// LDS 35.8 KB; __launch_bounds__(512,6) -> 3 blocks/CU (was 2).
//
// v register layout (pair-local): at stage u, lane L holds BOTH partners:
//   vlo = row ((L>>u)<<(u+1)) | (L & (2^u-1)),  vhi = vlo + 2^u
// -> mix is pure in-thread VALU; between stages each lane exchanges exactly
// one value with lane L^2^u (DPP quad_perm / ds_swizzle xor / ds_bpermute),
// fused into the mix.
// ---------------------------------------------------------------------------

typedef __bf16 bf16x8 __attribute__((ext_vector_type(8)));
typedef float  f32x4  __attribute__((ext_vector_type(4)));

#define XSTR 136                    // bf16 elems per xb row (128 + 8 pad)
#define XB_BYTES  (128 * XSTR * 2)  // 34816
#define WT_OFF    XB_BYTES
#define LDS_MAIN  (WT_OFF + 2 * 128 * 4)  // 35840 -> LDS allows 4 WGs/CU
#define PREP_LDS  (2 * XB_BYTES)    // 69632

__device__ __forceinline__ float ubits(unsigned int u) {
    union { unsigned int u; float f; } v; v.u = u; return v.f;
}
__device__ __forceinline__ unsigned short f2bf(float f) {
    union { float f; unsigned int u; } v; v.f = f;
    unsigned int u = v.u;
    return (unsigned short)((u + 0x7fffu + ((u >> 16) & 1u)) >> 16);
}

#define DPP_MOV_F(x, ctrl) \
    __int_as_float(__builtin_amdgcn_update_dpp(0, __float_as_int(x), (ctrl), 0xF, 0xF, true))

// cross-lane xor exchange with lane ^ (1<<u); u is compile-time-folded
__device__ __forceinline__ float xlane_u(float x, int u, int lane) {
    if (u == 0) return DPP_MOV_F(x, 0xB1);   // quad_perm xor1
    if (u == 1) return DPP_MOV_F(x, 0x4E);   // quad_perm xor2
    if (u == 2) return __int_as_float(__builtin_amdgcn_ds_swizzle(__float_as_int(x), 0x101F)); // xor4
    if (u == 3) return __int_as_float(__builtin_amdgcn_ds_swizzle(__float_as_int(x), 0x201F)); // xor8
    if (u == 4) return __int_as_float(__builtin_amdgcn_ds_swizzle(__float_as_int(x), 0x401F)); // xor16
    return __int_as_float(__builtin_amdgcn_ds_bpermute((lane ^ 32) << 2, __float_as_int(x))); // xor32
}

// ---------------- prep: PT[s][n][k] = scale * sum_e Wq[k][e] Wk[n][e] -------
// (unchanged; stored row n = P^T row: PT[c][e] = scale * P[e][c])
__global__ __launch_bounds__(512)
void prep_kernel(const float* __restrict__ qkw, unsigned short* __restrict__ PT) {
    extern __shared__ char smem[];
    unsigned short* wkb = (unsigned short*)smem;              // A: Wk rows (n)
    unsigned short* wqb = (unsigned short*)(smem + XB_BYTES); // B: Wq rows (k)
    const int s = blockIdx.x;
    const float* Wq = qkw + (size_t)s * 32768;
    const float* Wk = Wq + 16384;
    const int tid = threadIdx.x;
    const int rl = tid >> 5, c4 = tid & 31;
#pragma unroll
    for (int j = 0; j < 8; ++j) {
        int r = j * 16 + rl;
        float4 vq = ((const float4*)Wq)[r * 32 + c4];
        float4 vk = ((const float4*)Wk)[r * 32 + c4];
        ushort4 uq; uq.x = f2bf(vq.x); uq.y = f2bf(vq.y); uq.z = f2bf(vq.z); uq.w = f2bf(vq.w);
        ushort4 uk; uk.x = f2bf(vk.x); uk.y = f2bf(vk.y); uk.z = f2bf(vk.z); uk.w = f2bf(vk.w);
        *(ushort4*)(wqb + r * XSTR + c4 * 4) = uq;
        *(ushort4*)(wkb + r * XSTR + c4 * 4) = uk;
    }
    __syncthreads();
    const int lane = tid & 63, w = tid >> 6;
    const int lane15 = lane & 15, quad = lane >> 4;
    f32x4 acc[8] = {};
#pragma unroll
    for (int kk = 0; kk < 4; ++kk) {
        bf16x8 a = *(const bf16x8*)(wkb + (w * 16 + lane15) * XSTR + kk * 32 + quad * 8);
#pragma unroll
        for (int ct = 0; ct < 8; ++ct) {
            bf16x8 b = *(const bf16x8*)(wqb + (ct * 16 + lane15) * XSTR + kk * 32 + quad * 8);
            acc[ct] = __builtin_amdgcn_mfma_f32_16x16x32_bf16(a, b, acc[ct], 0, 0, 0);
        }
    }
    unsigned short* dst = PT + s * 16384;
#pragma unroll
    for (int ct = 0; ct < 8; ++ct)
#pragma unroll
        for (int r = 0; r < 4; ++r) {
            int n = w * 16 + quad * 4 + r;
            int k = ct * 16 + lane15;
            dst[n * 128 + k] = f2bf(acc[ct][r] * 0.17677669529663687f);
        }
}

// ---------------- fused butterfly stages ------------------------------------
template<int NS>
__global__ __launch_bounds__(512, 6)
void butterfly_kernel(const float* __restrict__ xsrc,
                      const float* __restrict__ vsrc,
                      float* __restrict__ vdst,
                      const unsigned short* __restrict__ PT,
                      int s0, int base_mul, int h_off, int rstride)
{
    extern __shared__ char smem[];
    unsigned short* xb = (unsigned short*)smem;
    float*          wt = (float*)(smem + WT_OFF);   // [2][128] double-buffered

    const int tid  = threadIdx.x;
    const int b    = blockIdx.x >> 6;
    const int sub  = blockIdx.x & 63;
    const int base = b * 8192 + sub * base_mul;

    // ---- stage x -> xb (bf16), coalesced ----
    {
        const int rl = tid >> 5, c4 = tid & 31;
#pragma unroll
        for (int j = 0; j < 8; ++j) {
            int i  = j * 16 + rl;
            int gp = base + (i >> 6) * h_off + (i & 63) * rstride;
            float4 val = ((const float4*)xsrc)[gp * 32 + c4];
            ushort4 us; us.x = f2bf(val.x); us.y = f2bf(val.y);
            us.z = f2bf(val.z); us.w = f2bf(val.w);
            *(ushort4*)(xb + i * XSTR + c4 * 4) = us;
        }
    }

    const int lane = tid & 63, w = tid >> 6;
    const int lane15 = lane & 15, quad = lane >> 4;
    const int nt = w & 3;          // pair tile: pairs nt*16..nt*16+15
    const int mh = w >> 2;         // k-half: dims mh*64..mh*64+63
    const int p  = nt * 16 + lane15;   // this lane's pair (GEMM/dot role)

    // ---- v into registers, pair-local for stage 0: rows (2L, 2L+1) ----
    float vlo[16], vhi[16];
    {
        int r0 = 2 * lane, r1 = r0 + 1;
        int gp0 = base + (r0 >> 6) * h_off + (r0 & 63) * rstride;
        int gp1 = base + (r1 >> 6) * h_off + (r1 & 63) * rstride;
        const float* p0 = vsrc + (size_t)gp0 * 128 + w * 16;
        const float* p1 = vsrc + (size_t)gp1 * 128 + w * 16;
#pragma unroll
        for (int j = 0; j < 4; ++j) {
            float4 a = ((const float4*)p0)[j];
            float4 c = ((const float4*)p1)[j];
            vlo[4*j] = a.x; vlo[4*j+1] = a.y; vlo[4*j+2] = a.z; vlo[4*j+3] = a.w;
            vhi[4*j] = c.x; vhi[4*j+1] = c.y; vhi[4*j+2] = c.z; vhi[4*j+3] = c.w;
        }
    }
    __syncthreads();   // xb ready

#pragma unroll
    for (int u = 0; u < NS; ++u) {
        const int t   = 1 << u;
        const int tm1 = t - 1;
        const int ar  = ((p & ~tm1) << 1) | (p & tm1);   // xb row of pair p's 'a'

        // ---- Gt = P^T @ Xa^T : wave-local 16x(4x16) tile, acc in registers.
        // A-frag: PT row c (c = mh*64 + mt*16 + lane15), k contiguous.
        // B-frag: xb row ar(p) (p = nt*16 + lane15), k contiguous.
        // C: col(lane15)=pair, row(quad*4+r)=c  -> dot is in-wave.
        float sm = 0.f;
        {
            const unsigned short* PTs  = PT + (s0 + u) * 16384;
            const unsigned short* arow = PTs + (mh * 64 + lane15) * 128 + quad * 8;
            const unsigned short* brow = xb + ar * XSTR + quad * 8;
            f32x4 acc[4] = {};
#pragma unroll
            for (int kk = 0; kk < 4; ++kk) {
                bf16x8 bfrag = *(const bf16x8*)(brow + kk * 32);
#pragma unroll
                for (int mt = 0; mt < 4; ++mt) {
                    bf16x8 afrag = *(const bf16x8*)(arow + mt * 2048 + kk * 32);
                    acc[mt] = __builtin_amdgcn_mfma_f32_16x16x32_bf16(afrag, bfrag, acc[mt], 0, 0, 0);
                }
            }
            // ---- in-register partial dot: sum_c Gt[c][p] * (xa[p][c]-xb[p][c])
            const unsigned short* da = xb + ar * XSTR + mh * 64 + quad * 4;
            const unsigned short* db = da + t * XSTR;
#pragma unroll
            for (int mt = 0; mt < 4; ++mt) {
                uint2 ua = *(const uint2*)(da + mt * 16);
                uint2 ub = *(const uint2*)(db + mt * 16);
                float a0 = ubits(ua.x << 16), a1 = ubits(ua.x & 0xffff0000u);
                float a2 = ubits(ua.y << 16), a3 = ubits(ua.y & 0xffff0000u);
                float b0 = ubits(ub.x << 16), b1 = ubits(ub.x & 0xffff0000u);
                float b2 = ubits(ub.y << 16), b3 = ubits(ub.y & 0xffff0000u);
                sm += acc[mt][0] * (a0 - b0) + acc[mt][1] * (a1 - b1)
                    + acc[mt][2] * (a2 - b2) + acc[mt][3] * (a3 - b3);
            }
        }
        // reduce over quads (lanes ^16, ^32 share lane15/pair)
        sm += xlane_u(sm, 4, lane);
        sm += xlane_u(sm, 5, lane);
        if (lane < 16) wt[(u & 1) * 128 + mh * 64 + nt * 16 + lane] = sm;
        __syncthreads();   // wt ready (single barrier per stage; wt dbuf'd)

        // ---- mix (in-thread) + fused pair exchange for next stage ----
        {
            const float d  = wt[(u & 1) * 128 + lane] + wt[(u & 1) * 128 + 64 + lane];
            const float w0 = 1.0f / (1.0f + __expf(-d));
            if (u < NS - 1) {
                const bool isE = ((lane >> u) & 1) == 0;
                const float wk = isE ? w0 : 1.0f - w0;
#pragma unroll
                for (int j = 0; j < 16; ++j) {
                    float a = vlo[j], c = vhi[j];
                    float s    = a + c;
                    float keep = c + wk * (a - c);   // E: out_a ; O: out_b
                    float send = s - keep;           // E: out_b ; O: out_a
                    float ex   = xlane_u(send, u, lane);
                    vlo[j] = isE ? keep : ex;
                    vhi[j] = isE ? ex : keep;
                }
            } else {
                const float w1 = 1.0f - w0;
#pragma unroll
                for (int j = 0; j < 16; ++j) {
                    float a = vlo[j], c = vhi[j];
                    float oa = w0 * a + w1 * c;
                    vlo[j] = oa;
                    vhi[j] = a + c - oa;
                }
            }
        }
    }

    // ---- store v registers -> vdst (layout of final stage NS-1) ----
    {
        const int FU = NS - 1;
        int r0 = ((lane >> FU) << (FU + 1)) | (lane & ((1 << FU) - 1));
        int r1 = r0 + (1 << FU);
        int gp0 = base + (r0 >> 6) * h_off + (r0 & 63) * rstride;
        int gp1 = base + (r1 >> 6) * h_off + (r1 & 63) * rstride;
        float* p0 = vdst + (size_t)gp0 * 128 + w * 16;
        float* p1 = vdst + (size_t)gp1 * 128 + w * 16;
#pragma unroll
        for (int j = 0; j < 4; ++j) {
            float4 a; a.x = vlo[4*j]; a.y = vlo[4*j+1]; a.z = vlo[4*j+2]; a.w = vlo[4*j+3];
            float4 c; c.x = vhi[4*j]; c.y = vhi[4*j+1]; c.z = vhi[4*j+2]; c.w = vhi[4*j+3];
            ((float4*)p0)[j] = a;
            ((float4*)p1)[j] = c;
        }
    }
}

extern "C" void kernel_launch(void* const* d_in, const int* in_sizes, int n_in,
                              void* d_out, int out_size, void* d_ws, size_t ws_size,
                              hipStream_t stream) {
    const float* x   = (const float*)d_in[0];
    const float* qkw = (const float*)d_in[1];
    float* out = (float*)d_out;
    unsigned short* PT = (unsigned short*)d_ws;   // 13*16384 bf16 = 416 KB

    (void)hipFuncSetAttribute((const void*)prep_kernel,
                              hipFuncAttributeMaxDynamicSharedMemorySize, PREP_LDS);
    (void)hipFuncSetAttribute((const void*)butterfly_kernel<7>,
                              hipFuncAttributeMaxDynamicSharedMemorySize, LDS_MAIN);
    (void)hipFuncSetAttribute((const void*)butterfly_kernel<6>,
                              hipFuncAttributeMaxDynamicSharedMemorySize, LDS_MAIN);

    prep_kernel<<<13, 512, PREP_LDS, stream>>>(qkw, PT);

    // stages 0..6: contiguous 128-position blocks; v init = x
    butterfly_kernel<7><<<1024, 512, LDS_MAIN, stream>>>(
        x, x, out, PT, /*s0=*/0, /*base_mul=*/128, /*h_off=*/64, /*rstride=*/1);

    // stages 7..12: 2 lo x 64 hi (stride 128); in-place on d_out
    butterfly_kernel<6><<<1024, 512, LDS_MAIN, stream>>>(
        x, out, out, PT, /*s0=*/7, /*base_mul=*/2, /*h_off=*/1, /*rstride=*/128);
}